// Round 9
// baseline (268.446 us; speedup 1.0000x reference)
//
#include <hip/hip_runtime.h>
#include <hip/hip_bf16.h>
#include <stdint.h>
#include <stddef.h>

#define S_LEN 4096
#define DMODEL 1024
#define NHEAD 16
#define HDIM 64
#define L2E 1.4426950408889634f

typedef __attribute__((ext_vector_type(8))) short bf16x8;
typedef __attribute__((ext_vector_type(8))) unsigned short u16x8;
typedef __attribute__((ext_vector_type(4))) float f32x4;
typedef __attribute__((ext_vector_type(16))) float f32x16;

__device__ __forceinline__ unsigned short f2bf(float f) {
    unsigned int u = __float_as_uint(f);
    return (unsigned short)((u + 0x7FFFu + ((u >> 16) & 1u)) >> 16);
}

// ---------------- RoPE table: cos/sin [4096][32] ----------------
__global__ __launch_bounds__(256) void rope_table_kernel(float* __restrict__ ctab,
                                                         float* __restrict__ stab) {
    int i = blockIdx.x * 256 + threadIdx.x;
    int s = i >> 5, j = i & 31;
    float freq = exp2f(-0.41524101186092407f * (float)j);   // 10000^(-j/32)
    float ang = (float)s * freq;
    ctab[i] = cosf(ang);
    stab[i] = sinf(ang);
}

// ---------------- W [K][N] f32 -> Wt [N][K] bf16 (transpose) ----------------
__global__ __launch_bounds__(256) void cvt_wt_kernel(
    const float* __restrict__ w0, const float* __restrict__ w1,
    const float* __restrict__ w2, const float* __restrict__ w3,
    unsigned short* __restrict__ t0, unsigned short* __restrict__ t1,
    unsigned short* __restrict__ t2, unsigned short* __restrict__ t3) {
    const float* src; unsigned short* dst;
    switch (blockIdx.z) {
        case 0: src = w0; dst = t0; break;
        case 1: src = w1; dst = t1; break;
        case 2: src = w2; dst = t2; break;
        default: src = w3; dst = t3; break;
    }
    __shared__ float tile[64][65];
    int t = threadIdx.x;
    int k0 = blockIdx.y * 64, n0 = blockIdx.x * 64;
    int r = t >> 2, q4 = (t & 3) * 16;
    const float* sp = src + (size_t)(k0 + r) * DMODEL + n0 + q4;
    #pragma unroll
    for (int j = 0; j < 4; ++j) {
        f32x4 v = *(const f32x4*)(sp + j * 4);
        #pragma unroll
        for (int e = 0; e < 4; ++e) tile[r][q4 + j * 4 + e] = v[e];
    }
    __syncthreads();
    int n = t >> 2, kq = (t & 3) * 16;
    unsigned short* dp = dst + (size_t)(n0 + n) * DMODEL + k0 + kq;
    u16x8 a, b;
    #pragma unroll
    for (int j = 0; j < 8; ++j) { a[j] = f2bf(tile[kq + j][n]); b[j] = f2bf(tile[kq + 8 + j][n]); }
    *(u16x8*)dp = a;
    *(u16x8*)(dp + 8) = b;
}

// ---------------- GEMM 128x128x64, 4 waves, 16x16x32 bf16 MFMA ----------------
template<int MODE>
__global__ __launch_bounds__(256) void gemm_kernel(
    const float* __restrict__ Af,
    const unsigned short* __restrict__ Ab,
    const unsigned short* __restrict__ B0,
    const unsigned short* __restrict__ B1,
    const unsigned short* __restrict__ B2,
    unsigned short* __restrict__ o0,
    unsigned short* __restrict__ o1,
    unsigned short* __restrict__ o2,
    float* __restrict__ fo,
    const float* __restrict__ ctab,
    const float* __restrict__ stab) {
    int z = blockIdx.z;
    const unsigned short* Bt = (MODE == 0) ? B0 : (z == 0 ? B0 : (z == 1 ? B1 : B2));
    unsigned short* outp     = (MODE == 0) ? o0 : (z == 0 ? o0 : (z == 1 ? o1 : o2));
    int m0 = blockIdx.y * 128, n0 = blockIdx.x * 128;
    __shared__ unsigned short As[128][72];
    __shared__ unsigned short Bs[128][72];
    int t = threadIdx.x, w = t >> 6, l = t & 63;
    int wm = w >> 1, wn = w & 1, g = l >> 4, c = l & 15;

    f32x4 acc[4][4];
    #pragma unroll
    for (int m = 0; m < 4; ++m)
        #pragma unroll
        for (int n = 0; n < 4; ++n) acc[m][n] = (f32x4){0.f, 0.f, 0.f, 0.f};

    int sr = t >> 1, scc = (t & 1) * 32;

    for (int kt = 0; kt < DMODEL; kt += 64) {
        __syncthreads();
        if (MODE == 1) {
            const float* gp = Af + (size_t)(m0 + sr) * DMODEL + kt + scc;
            #pragma unroll
            for (int j = 0; j < 4; ++j) {
                f32x4 lo = *(const f32x4*)(gp + j * 8);
                f32x4 hi = *(const f32x4*)(gp + j * 8 + 4);
                u16x8 o;
                #pragma unroll
                for (int e = 0; e < 4; ++e) { o[e] = f2bf(lo[e]); o[4 + e] = f2bf(hi[e]); }
                *(u16x8*)&As[sr][scc + j * 8] = o;
            }
        } else {
            const unsigned short* gp = Ab + (size_t)(m0 + sr) * DMODEL + kt + scc;
            #pragma unroll
            for (int j = 0; j < 4; ++j)
                *(u16x8*)&As[sr][scc + j * 8] = *(const u16x8*)(gp + j * 8);
        }
        {
            const unsigned short* gp = Bt + (size_t)(n0 + sr) * DMODEL + kt + scc;
            #pragma unroll
            for (int j = 0; j < 4; ++j)
                *(u16x8*)&Bs[sr][scc + j * 8] = *(const u16x8*)(gp + j * 8);
        }
        __syncthreads();
        #pragma unroll
        for (int kk = 0; kk < 64; kk += 32) {
            bf16x8 af[4], bf[4];
            #pragma unroll
            for (int m = 0; m < 4; ++m) af[m] = *(const bf16x8*)&As[wm * 64 + m * 16 + c][kk + g * 8];
            #pragma unroll
            for (int n = 0; n < 4; ++n) bf[n] = *(const bf16x8*)&Bs[wn * 64 + n * 16 + c][kk + g * 8];
            #pragma unroll
            for (int m = 0; m < 4; ++m)
                #pragma unroll
                for (int n = 0; n < 4; ++n)
                    acc[m][n] = __builtin_amdgcn_mfma_f32_16x16x32_bf16(af[m], bf[n], acc[m][n], 0, 0, 0);
        }
    }

    if (MODE == 1 && z < 2) {
        // q: fold 1/sqrt(64) AND log2(e) so attention scores are in log2 domain
        float sc8 = (z == 0) ? 0.125f * L2E : 1.0f;
        #pragma unroll
        for (int m = 0; m < 4; ++m) {
            #pragma unroll
            for (int r = 0; r < 4; ++r) {
                int srow = m0 + wm * 64 + m * 16 + g * 4 + r;
                #pragma unroll
                for (int n = 0; n < 2; ++n) {
                    int e = n * 16 + c;                      // e < 32 within head
                    float cs = ctab[srow * 32 + e];
                    float sn = stab[srow * 32 + e];
                    float lo = acc[m][n][r], hi = acc[m][n + 2][r];
                    float nlo = (lo * cs - hi * sn) * sc8;
                    float nhi = (hi * cs + lo * sn) * sc8;
                    size_t base = (size_t)srow * DMODEL + n0 + wn * 64;
                    outp[base + n * 16 + c]       = f2bf(nlo);
                    outp[base + (n + 2) * 16 + c] = f2bf(nhi);
                }
            }
        }
    } else if (MODE == 1) {
        #pragma unroll
        for (int m = 0; m < 4; ++m)
            #pragma unroll
            for (int r = 0; r < 4; ++r) {
                int srow = m0 + wm * 64 + m * 16 + g * 4 + r;
                size_t base = (size_t)srow * DMODEL + n0 + wn * 64;
                #pragma unroll
                for (int n = 0; n < 4; ++n)
                    outp[base + n * 16 + c] = f2bf(acc[m][n][r]);
            }
    } else {
        #pragma unroll
        for (int m = 0; m < 4; ++m)
            #pragma unroll
            for (int r = 0; r < 4; ++r) {
                int srow = m0 + wm * 64 + m * 16 + g * 4 + r;
                size_t base = (size_t)srow * DMODEL + n0 + wn * 64;
                #pragma unroll
                for (int n = 0; n < 4; ++n)
                    fo[base + n * 16 + c] = acc[m][n][r];
            }
    }
}

// ---------------- causal flash attention, 32x32 swapped-QK^T, in-reg softmax ----
// Block = 128 q-rows x 1 head, 4 waves x 32 rows. Per 64-key tile: two 32-key
// halves. S^T = mfma32(K, Q^T): lane holds 16 key-scores of ONE q-row
// (col=lane&31=qrow [m74/m101]); softmax is in-lane + one xor-32 shuffle;
// P repacks to the PV A-fragment with 4 permlane32_swap (no LDS). m/lsum are
// lane-local. O rows live in regs; lsum/alpha broadcast via width-32 shfl.
__global__ __launch_bounds__(256) void attn_kernel(
    const unsigned short* __restrict__ q,
    const unsigned short* __restrict__ k,
    const unsigned short* __restrict__ v,
    unsigned short* __restrict__ ctx) {
    int h = blockIdx.x;                              // head -> XCD cluster
    int qb = 31 - (int)blockIdx.y;                   // big blocks dispatch first
    int t = threadIdx.x, w = t >> 6, l = t & 63, c = l & 31, hi = l >> 5;

    __shared__ unsigned short Ks[64][72];            // [key][dim]
    __shared__ unsigned short Vt[64][72];            // [dim][key]

    int qrow = qb * 128 + w * 32 + c;                // this lane's q-row
    int wrmax = qb * 128 + w * 32 + 31;

    // Q fragments: B-operand col=lane&31=qrow, k=(lane>>5)*8+i; 4 K-steps of 16
    bf16x8 qf[4];
    {
        const unsigned short* qp = q + (size_t)qrow * DMODEL + h * HDIM + hi * 8;
        #pragma unroll
        for (int s = 0; s < 4; ++s) qf[s] = *(const bf16x8*)(qp + s * 16);
    }

    f32x16 o0, o1;
    #pragma unroll
    for (int i = 0; i < 16; ++i) { o0[i] = 0.f; o1[i] = 0.f; }
    float m = -3.0e38f, lsum = 0.f;

    int skr = t >> 2, skc = (t & 3) * 16;
    int svr = t & 63, svc = (t >> 6) * 16;
    const unsigned short* gkb = k + (size_t)skr * DMODEL + h * HDIM + skc;
    const unsigned short* gvb = v + (size_t)svr * DMODEL + h * HDIM + svc;

    int nt = 2 * qb + 2;
    u16x8 ka, kb, va, vb;
    ka = *(const u16x8*)gkb;
    kb = *(const u16x8*)(gkb + 8);
    va = *(const u16x8*)gvb;
    vb = *(const u16x8*)(gvb + 8);
    *(u16x8*)&Ks[skr][skc]     = ka;
    *(u16x8*)&Ks[skr][skc + 8] = kb;
    #pragma unroll
    for (int j = 0; j < 8; ++j) {
        Vt[svc + j][svr]     = va[j];
        Vt[svc + 8 + j][svr] = vb[j];
    }

    for (int kt = 0; kt < nt; ++kt) {
        int kv0 = kt * 64;
        if (kt + 1 < nt) {              // prefetch next tile into regs
            size_t off = (size_t)(kv0 + 64) * DMODEL;
            ka = *(const u16x8*)(gkb + off);
            kb = *(const u16x8*)(gkb + off + 8);
            va = *(const u16x8*)(gvb + off);
            vb = *(const u16x8*)(gvb + off + 8);
        }
        __syncthreads();                // tile kt staged

        #pragma unroll
        for (int h2 = 0; h2 < 2; ++h2) {
            int kbase = kv0 + h2 * 32;
            if (kbase > wrmax) continue;            // fully-masked half

            // S^T = K x Q^T over 64 dims (4 K-steps)
            f32x16 sf;
            #pragma unroll
            for (int i = 0; i < 16; ++i) sf[i] = 0.f;
            __builtin_amdgcn_s_setprio(1);
            #pragma unroll
            for (int s = 0; s < 4; ++s) {
                bf16x8 kf = *(const bf16x8*)&Ks[h2 * 32 + c][s * 16 + hi * 8];
                sf = __builtin_amdgcn_mfma_f32_32x32x16_bf16(kf, qf[s], sf, 0, 0, 0);
            }
            __builtin_amdgcn_s_setprio(0);

            // causal mask: both kbase and wave row-base are multiples of 32, so
            // the only partially-masked half is kbase == row-base, i.e.
            // kbase + 31 >= wrmax.  (round-8 bug: used '>' -> mask never fired)
            if (kbase + 31 >= wrmax) {
                #pragma unroll
                for (int r = 0; r < 16; ++r) {
                    int key = kbase + (r & 3) + 8 * (r >> 2) + 4 * hi;
                    if (key > qrow) sf[r] = -3.0e38f;
                }
            }

            // in-lane max over 16 + one cross-half shuffle
            float tm = sf[0];
            #pragma unroll
            for (int r = 1; r < 16; ++r) tm = fmaxf(tm, sf[r]);
            tm = fmaxf(tm, __shfl_xor(tm, 32, 64));

            if (!__all(tm <= m + 8.f)) {            // rescale (rare: defer-max)
                float mn = fmaxf(m, tm);
                float al = exp2f(m - mn);
                m = mn;
                lsum *= al;
                #pragma unroll
                for (int r = 0; r < 16; ++r) {
                    float ar = __shfl(al, (r & 3) + 8 * (r >> 2) + 4 * hi, 32);
                    o0[r] *= ar;
                    o1[r] *= ar;
                }
            }

            // P = 2^(s-m) truncated to bf16; psum over truncated values
            float ps = 0.f;
            unsigned int dw[8];
            #pragma unroll
            for (int j = 0; j < 8; ++j) {
                float p0 = exp2f(sf[2 * j]     - m);
                float p1 = exp2f(sf[2 * j + 1] - m);
                unsigned int u0 = __float_as_uint(p0) & 0xFFFF0000u;
                unsigned int u1 = __float_as_uint(p1) & 0xFFFF0000u;
                ps += __uint_as_float(u0) + __uint_as_float(u1);
                dw[j] = (u0 >> 16) | u1;
            }
            ps += __shfl_xor(ps, 32, 64);
            lsum += ps;

            // repack to PV A-fragment: swap pairs -> (s.d0,s.d2),(s.d1,s.d3)
            {
                auto r0 = __builtin_amdgcn_permlane32_swap(dw[0], dw[2], false, false);
                dw[0] = r0[0]; dw[2] = r0[1];
                auto r1 = __builtin_amdgcn_permlane32_swap(dw[1], dw[3], false, false);
                dw[1] = r1[0]; dw[3] = r1[1];
                auto r2 = __builtin_amdgcn_permlane32_swap(dw[4], dw[6], false, false);
                dw[4] = r2[0]; dw[6] = r2[1];
                auto r3 = __builtin_amdgcn_permlane32_swap(dw[5], dw[7], false, false);
                dw[5] = r3[0]; dw[7] = r3[1];
            }
            union { unsigned int u[8]; bf16x8 v[2]; } pu;
            #pragma unroll
            for (int j = 0; j < 8; ++j) pu.u[j] = dw[j];

            // PV: O[qrow][dim] A=P (row=qrow, k=key), B=V^T-read (col=dim)
            __builtin_amdgcn_s_setprio(1);
            {
                bf16x8 vf00 = *(const bf16x8*)&Vt[c][kbase - kv0 + hi * 8];
                bf16x8 vf01 = *(const bf16x8*)&Vt[c][kbase - kv0 + 16 + hi * 8];
                bf16x8 vf10 = *(const bf16x8*)&Vt[32 + c][kbase - kv0 + hi * 8];
                bf16x8 vf11 = *(const bf16x8*)&Vt[32 + c][kbase - kv0 + 16 + hi * 8];
                o0 = __builtin_amdgcn_mfma_f32_32x32x16_bf16(pu.v[0], vf00, o0, 0, 0, 0);
                o0 = __builtin_amdgcn_mfma_f32_32x32x16_bf16(pu.v[1], vf01, o0, 0, 0, 0);
                o1 = __builtin_amdgcn_mfma_f32_32x32x16_bf16(pu.v[0], vf10, o1, 0, 0, 0);
                o1 = __builtin_amdgcn_mfma_f32_32x32x16_bf16(pu.v[1], vf11, o1, 0, 0, 0);
            }
            __builtin_amdgcn_s_setprio(0);
        }

        if (kt + 1 < nt) {
            __syncthreads();            // all waves done with tile kt
            *(u16x8*)&Ks[skr][skc]     = ka;
            *(u16x8*)&Ks[skr][skc + 8] = kb;
            #pragma unroll
            for (int j = 0; j < 8; ++j) {
                Vt[svc + j][svr]     = va[j];
                Vt[svc + 8 + j][svr] = vb[j];
            }
        }
    }

    // normalize + store: O row r -> qrow qb*128+w*32+rl(r,hi)
    float inv = 1.0f / lsum;
    #pragma unroll
    for (int r = 0; r < 16; ++r) {
        int rl = (r & 3) + 8 * (r >> 2) + 4 * hi;
        float invr = __shfl(inv, rl, 32);
        int grow = qb * 128 + w * 32 + rl;
        size_t base = (size_t)grow * DMODEL + h * HDIM + c;
        ctx[base]      = f2bf(o0[r] * invr);
        ctx[base + 32] = f2bf(o1[r] * invr);
    }
}

extern "C" void kernel_launch(void* const* d_in, const int* in_sizes, int n_in,
                              void* d_out, int out_size, void* d_ws, size_t ws_size,
                              hipStream_t stream) {
    const float* x  = (const float*)d_in[0];
    // d_in[1] = causal mask (tril by construction) — unused
    const float* Wq = (const float*)d_in[2];
    const float* Wk = (const float*)d_in[3];
    const float* Wv = (const float*)d_in[4];
    const float* Wo = (const float*)d_in[5];

    // ws layout (peak 35 MB):
    //   [0,0.5M) ctab  [0.5M,1M) stab
    //   [1M,9M)  ctx  (overlays Wtq/Wtk/Wtv, dead after QKV gemm)
    //   [1M,3M) Wtq  [3M,5M) Wtk  [5M,7M) Wtv
    //   [9M,11M) Wto
    //   [11M,19M) kr  [19M,27M) vb  [27M,35M) qr
    char* ws = (char*)d_ws;
    float* ctab = (float*)(ws);
    float* stab = (float*)(ws + (512u << 10));
    unsigned short* ctx = (unsigned short*)(ws + (1u  << 20));
    unsigned short* Wtq = (unsigned short*)(ws + (1u  << 20));
    unsigned short* Wtk = (unsigned short*)(ws + (3u  << 20));
    unsigned short* Wtv = (unsigned short*)(ws + (5u  << 20));
    unsigned short* Wto = (unsigned short*)(ws + (9u  << 20));
    unsigned short* kr  = (unsigned short*)(ws + (11u << 20));
    unsigned short* vb  = (unsigned short*)(ws + (19u << 20));
    unsigned short* qr  = (unsigned short*)(ws + (27u << 20));

    rope_table_kernel<<<(S_LEN * 32) / 256, 256, 0, stream>>>(ctab, stab);
    cvt_wt_kernel<<<dim3(16, 16, 4), 256, 0, stream>>>(Wq, Wk, Wv, Wo, Wtq, Wtk, Wtv, Wto);
    gemm_kernel<1><<<dim3(8, 32, 3), 256, 0, stream>>>(x, nullptr, Wtq, Wtk, Wtv,
                                                       qr, kr, vb, nullptr, ctab, stab);
    attn_kernel<<<dim3(16, 32), 256, 0, stream>>>(qr, kr, vb, ctx);
    gemm_kernel<0><<<dim3(8, 32, 1), 256, 0, stream>>>(nullptr, ctx, Wto, nullptr, nullptr,
                                                       nullptr, nullptr, nullptr,
                                                       (float*)d_out, ctab, stab);
}

// Round 10
// 211.430 us; speedup vs baseline: 1.2697x; 1.2697x over previous
//
#include <hip/hip_runtime.h>
#include <hip/hip_bf16.h>
#include <stdint.h>
#include <stddef.h>

#define S_LEN 4096
#define DMODEL 1024
#define NHEAD 16
#define HDIM 64
#define L2E 1.4426950408889634f

typedef __attribute__((ext_vector_type(8))) short bf16x8;
typedef __attribute__((ext_vector_type(8))) unsigned short u16x8;
typedef __attribute__((ext_vector_type(4))) float f32x4;
typedef __attribute__((ext_vector_type(16))) float f32x16;

__device__ __forceinline__ unsigned short f2bf(float f) {
    unsigned int u = __float_as_uint(f);
    return (unsigned short)((u + 0x7FFFu + ((u >> 16) & 1u)) >> 16);
}

// ---------------- RoPE table: cos/sin [4096][32] ----------------
__global__ __launch_bounds__(256) void rope_table_kernel(float* __restrict__ ctab,
                                                         float* __restrict__ stab) {
    int i = blockIdx.x * 256 + threadIdx.x;
    int s = i >> 5, j = i & 31;
    float freq = exp2f(-0.41524101186092407f * (float)j);   // 10000^(-j/32)
    float ang = (float)s * freq;
    ctab[i] = cosf(ang);
    stab[i] = sinf(ang);
}

// ---------------- W [K][N] f32 -> Wt [N][K] bf16 (transpose) ----------------
__global__ __launch_bounds__(256) void cvt_wt_kernel(
    const float* __restrict__ w0, const float* __restrict__ w1,
    const float* __restrict__ w2, const float* __restrict__ w3,
    unsigned short* __restrict__ t0, unsigned short* __restrict__ t1,
    unsigned short* __restrict__ t2, unsigned short* __restrict__ t3) {
    const float* src; unsigned short* dst;
    switch (blockIdx.z) {
        case 0: src = w0; dst = t0; break;
        case 1: src = w1; dst = t1; break;
        case 2: src = w2; dst = t2; break;
        default: src = w3; dst = t3; break;
    }
    __shared__ float tile[64][65];
    int t = threadIdx.x;
    int k0 = blockIdx.y * 64, n0 = blockIdx.x * 64;
    int r = t >> 2, q4 = (t & 3) * 16;
    const float* sp = src + (size_t)(k0 + r) * DMODEL + n0 + q4;
    #pragma unroll
    for (int j = 0; j < 4; ++j) {
        f32x4 v = *(const f32x4*)(sp + j * 4);
        #pragma unroll
        for (int e = 0; e < 4; ++e) tile[r][q4 + j * 4 + e] = v[e];
    }
    __syncthreads();
    int n = t >> 2, kq = (t & 3) * 16;
    unsigned short* dp = dst + (size_t)(n0 + n) * DMODEL + k0 + kq;
    u16x8 a, b;
    #pragma unroll
    for (int j = 0; j < 8; ++j) { a[j] = f2bf(tile[kq + j][n]); b[j] = f2bf(tile[kq + 8 + j][n]); }
    *(u16x8*)dp = a;
    *(u16x8*)(dp + 8) = b;
}

// ---------------- GEMM 128x128x64, 4 waves, 16x16x32 bf16 MFMA ----------------
template<int MODE>
__global__ __launch_bounds__(256) void gemm_kernel(
    const float* __restrict__ Af,
    const unsigned short* __restrict__ Ab,
    const unsigned short* __restrict__ B0,
    const unsigned short* __restrict__ B1,
    const unsigned short* __restrict__ B2,
    unsigned short* __restrict__ o0,
    unsigned short* __restrict__ o1,
    unsigned short* __restrict__ o2,
    float* __restrict__ fo,
    const float* __restrict__ ctab,
    const float* __restrict__ stab) {
    int z = blockIdx.z;
    const unsigned short* Bt = (MODE == 0) ? B0 : (z == 0 ? B0 : (z == 1 ? B1 : B2));
    unsigned short* outp     = (MODE == 0) ? o0 : (z == 0 ? o0 : (z == 1 ? o1 : o2));
    int m0 = blockIdx.y * 128, n0 = blockIdx.x * 128;
    __shared__ unsigned short As[128][72];
    __shared__ unsigned short Bs[128][72];
    int t = threadIdx.x, w = t >> 6, l = t & 63;
    int wm = w >> 1, wn = w & 1, g = l >> 4, c = l & 15;

    f32x4 acc[4][4];
    #pragma unroll
    for (int m = 0; m < 4; ++m)
        #pragma unroll
        for (int n = 0; n < 4; ++n) acc[m][n] = (f32x4){0.f, 0.f, 0.f, 0.f};

    int sr = t >> 1, scc = (t & 1) * 32;

    for (int kt = 0; kt < DMODEL; kt += 64) {
        __syncthreads();
        if (MODE == 1) {
            const float* gp = Af + (size_t)(m0 + sr) * DMODEL + kt + scc;
            #pragma unroll
            for (int j = 0; j < 4; ++j) {
                f32x4 lo = *(const f32x4*)(gp + j * 8);
                f32x4 hi = *(const f32x4*)(gp + j * 8 + 4);
                u16x8 o;
                #pragma unroll
                for (int e = 0; e < 4; ++e) { o[e] = f2bf(lo[e]); o[4 + e] = f2bf(hi[e]); }
                *(u16x8*)&As[sr][scc + j * 8] = o;
            }
        } else {
            const unsigned short* gp = Ab + (size_t)(m0 + sr) * DMODEL + kt + scc;
            #pragma unroll
            for (int j = 0; j < 4; ++j)
                *(u16x8*)&As[sr][scc + j * 8] = *(const u16x8*)(gp + j * 8);
        }
        {
            const unsigned short* gp = Bt + (size_t)(n0 + sr) * DMODEL + kt + scc;
            #pragma unroll
            for (int j = 0; j < 4; ++j)
                *(u16x8*)&Bs[sr][scc + j * 8] = *(const u16x8*)(gp + j * 8);
        }
        __syncthreads();
        #pragma unroll
        for (int kk = 0; kk < 64; kk += 32) {
            bf16x8 af[4], bf[4];
            #pragma unroll
            for (int m = 0; m < 4; ++m) af[m] = *(const bf16x8*)&As[wm * 64 + m * 16 + c][kk + g * 8];
            #pragma unroll
            for (int n = 0; n < 4; ++n) bf[n] = *(const bf16x8*)&Bs[wn * 64 + n * 16 + c][kk + g * 8];
            #pragma unroll
            for (int m = 0; m < 4; ++m)
                #pragma unroll
                for (int n = 0; n < 4; ++n)
                    acc[m][n] = __builtin_amdgcn_mfma_f32_16x16x32_bf16(af[m], bf[n], acc[m][n], 0, 0, 0);
        }
    }

    if (MODE == 1 && z < 2) {
        // q: fold 1/sqrt(64) AND log2(e) so attention scores are in log2 domain
        float sc8 = (z == 0) ? 0.125f * L2E : 1.0f;
        #pragma unroll
        for (int m = 0; m < 4; ++m) {
            #pragma unroll
            for (int r = 0; r < 4; ++r) {
                int srow = m0 + wm * 64 + m * 16 + g * 4 + r;
                #pragma unroll
                for (int n = 0; n < 2; ++n) {
                    int e = n * 16 + c;                      // e < 32 within head
                    float cs = ctab[srow * 32 + e];
                    float sn = stab[srow * 32 + e];
                    float lo = acc[m][n][r], hi = acc[m][n + 2][r];
                    float nlo = (lo * cs - hi * sn) * sc8;
                    float nhi = (hi * cs + lo * sn) * sc8;
                    size_t base = (size_t)srow * DMODEL + n0 + wn * 64;
                    outp[base + n * 16 + c]       = f2bf(nlo);
                    outp[base + (n + 2) * 16 + c] = f2bf(nhi);
                }
            }
        }
    } else if (MODE == 1) {
        #pragma unroll
        for (int m = 0; m < 4; ++m)
            #pragma unroll
            for (int r = 0; r < 4; ++r) {
                int srow = m0 + wm * 64 + m * 16 + g * 4 + r;
                size_t base = (size_t)srow * DMODEL + n0 + wn * 64;
                #pragma unroll
                for (int n = 0; n < 4; ++n)
                    outp[base + n * 16 + c] = f2bf(acc[m][n][r]);
            }
    } else {
        #pragma unroll
        for (int m = 0; m < 4; ++m)
            #pragma unroll
            for (int r = 0; r < 4; ++r) {
                int srow = m0 + wm * 64 + m * 16 + g * 4 + r;
                size_t base = (size_t)srow * DMODEL + n0 + wn * 64;
                #pragma unroll
                for (int n = 0; n < 4; ++n)
                    fo[base + n * 16 + c] = acc[m][n][r];
            }
    }
}

// ---------------- causal flash attention, 32x32 swapped-QK^T, in-reg softmax ----
// v4: 512 threads = 4 row-groups x 2 key-streams. Stream s handles tiles
// kt%2==s with its own LDS tile-pair and private (m,l,O); exact f32 merge at
// the end via LDS (overlays dead tile buffers). Per-half-tile math identical
// to the verified round-9 kernel.
__global__ __launch_bounds__(512) void attn_kernel(
    const unsigned short* __restrict__ q,
    const unsigned short* __restrict__ k,
    const unsigned short* __restrict__ v,
    unsigned short* __restrict__ ctx) {
    int h = blockIdx.x;                              // head -> XCD cluster
    int qb = 31 - (int)blockIdx.y;                   // big blocks dispatch first
    int t = threadIdx.x, w = t >> 6, l = t & 63, c = l & 31, hi = l >> 5;
    int rg = w & 3, ks = w >> 2;                     // row-group, key-stream

    __shared__ __align__(16) char smraw[36864];
    unsigned short (*KsT)[64][72] = (unsigned short (*)[64][72])smraw;           // [2][64][72]
    unsigned short (*VtT)[64][72] = (unsigned short (*)[64][72])(smraw + 18432); // [2][64][72]
    float (*Om)[32][64] = (float (*)[32][64])smraw;                              // [4][32][64]
    float (*ml)[2]      = (float (*)[2])(smraw + 32768);                         // [128][2]

    int qrow = qb * 128 + rg * 32 + c;               // this lane's q-row
    int wrmax = qb * 128 + rg * 32 + 31;

    bf16x8 qf[4];
    {
        const unsigned short* qp = q + (size_t)qrow * DMODEL + h * HDIM + hi * 8;
        #pragma unroll
        for (int s = 0; s < 4; ++s) qf[s] = *(const bf16x8*)(qp + s * 16);
    }

    f32x16 o0, o1;
    #pragma unroll
    for (int i = 0; i < 16; ++i) { o0[i] = 0.f; o1[i] = 0.f; }
    float m = -3.0e38f, lsum = 0.f;

    // staging ids within this stream's 256 threads
    int ts = t & 255;
    int skr = ts >> 2, skc = (ts & 3) * 16;
    int svr = ts & 63, svc = ((ts >> 6) & 3) * 16;
    const unsigned short* gkb = k + (size_t)skr * DMODEL + h * HDIM + skc;
    const unsigned short* gvb = v + (size_t)svr * DMODEL + h * HDIM + svc;

    int nit = qb + 1;                                // tiles per stream
    u16x8 ka, kb, va, vb;
    {   // prologue: stream's tile 0 = global tile index ks
        size_t off = (size_t)(ks * 64) * DMODEL;
        ka = *(const u16x8*)(gkb + off);
        kb = *(const u16x8*)(gkb + off + 8);
        va = *(const u16x8*)(gvb + off);
        vb = *(const u16x8*)(gvb + off + 8);
    }
    *(u16x8*)&KsT[ks][skr][skc]     = ka;
    *(u16x8*)&KsT[ks][skr][skc + 8] = kb;
    #pragma unroll
    for (int j = 0; j < 8; ++j) {
        VtT[ks][svc + j][svr]     = va[j];
        VtT[ks][svc + 8 + j][svr] = vb[j];
    }

    for (int it = 0; it < nit; ++it) {
        int kt = 2 * it + ks;                        // my stream's tile
        int kv0 = kt * 64;
        if (it + 1 < nit) {                          // prefetch tile kt+2
            size_t off = (size_t)(kv0 + 128) * DMODEL;
            ka = *(const u16x8*)(gkb + off);
            kb = *(const u16x8*)(gkb + off + 8);
            va = *(const u16x8*)(gvb + off);
            vb = *(const u16x8*)(gvb + off + 8);
        }
        __syncthreads();                             // tiles staged

        #pragma unroll
        for (int h2 = 0; h2 < 2; ++h2) {
            int kbase = kv0 + h2 * 32;
            if (kbase > wrmax) continue;             // fully-masked half

            f32x16 sf;
            #pragma unroll
            for (int i = 0; i < 16; ++i) sf[i] = 0.f;
            __builtin_amdgcn_s_setprio(1);
            #pragma unroll
            for (int s = 0; s < 4; ++s) {
                bf16x8 kf = *(const bf16x8*)&KsT[ks][h2 * 32 + c][s * 16 + hi * 8];
                sf = __builtin_amdgcn_mfma_f32_32x32x16_bf16(kf, qf[s], sf, 0, 0, 0);
            }
            __builtin_amdgcn_s_setprio(0);

            if (kbase + 31 >= wrmax) {               // diagonal half: causal mask
                #pragma unroll
                for (int r = 0; r < 16; ++r) {
                    int key = kbase + (r & 3) + 8 * (r >> 2) + 4 * hi;
                    if (key > qrow) sf[r] = -3.0e38f;
                }
            }

            float tm = sf[0];
            #pragma unroll
            for (int r = 1; r < 16; ++r) tm = fmaxf(tm, sf[r]);
            tm = fmaxf(tm, __shfl_xor(tm, 32, 64));

            if (!__all(tm <= m + 8.f)) {             // rescale (rare: defer-max)
                float mn = fmaxf(m, tm);
                float al = exp2f(m - mn);
                m = mn;
                lsum *= al;
                #pragma unroll
                for (int r = 0; r < 16; ++r) {
                    float ar = __shfl(al, (r & 3) + 8 * (r >> 2) + 4 * hi, 32);
                    o0[r] *= ar;
                    o1[r] *= ar;
                }
            }

            float ps = 0.f;
            unsigned int dw[8];
            #pragma unroll
            for (int j = 0; j < 8; ++j) {
                float p0 = exp2f(sf[2 * j]     - m);
                float p1 = exp2f(sf[2 * j + 1] - m);
                unsigned int u0 = __float_as_uint(p0) & 0xFFFF0000u;
                unsigned int u1 = __float_as_uint(p1) & 0xFFFF0000u;
                ps += __uint_as_float(u0) + __uint_as_float(u1);
                dw[j] = (u0 >> 16) | u1;
            }
            ps += __shfl_xor(ps, 32, 64);
            lsum += ps;

            {   // repack to PV A-fragment
                auto r0 = __builtin_amdgcn_permlane32_swap(dw[0], dw[2], false, false);
                dw[0] = r0[0]; dw[2] = r0[1];
                auto r1 = __builtin_amdgcn_permlane32_swap(dw[1], dw[3], false, false);
                dw[1] = r1[0]; dw[3] = r1[1];
                auto r2 = __builtin_amdgcn_permlane32_swap(dw[4], dw[6], false, false);
                dw[4] = r2[0]; dw[6] = r2[1];
                auto r3 = __builtin_amdgcn_permlane32_swap(dw[5], dw[7], false, false);
                dw[5] = r3[0]; dw[7] = r3[1];
            }
            union { unsigned int u[8]; bf16x8 v[2]; } pu;
            #pragma unroll
            for (int j = 0; j < 8; ++j) pu.u[j] = dw[j];

            __builtin_amdgcn_s_setprio(1);
            {
                bf16x8 vf00 = *(const bf16x8*)&VtT[ks][c][h2 * 32 + hi * 8];
                bf16x8 vf01 = *(const bf16x8*)&VtT[ks][c][h2 * 32 + 16 + hi * 8];
                bf16x8 vf10 = *(const bf16x8*)&VtT[ks][32 + c][h2 * 32 + hi * 8];
                bf16x8 vf11 = *(const bf16x8*)&VtT[ks][32 + c][h2 * 32 + 16 + hi * 8];
                o0 = __builtin_amdgcn_mfma_f32_32x32x16_bf16(pu.v[0], vf00, o0, 0, 0, 0);
                o0 = __builtin_amdgcn_mfma_f32_32x32x16_bf16(pu.v[1], vf01, o0, 0, 0, 0);
                o1 = __builtin_amdgcn_mfma_f32_32x32x16_bf16(pu.v[0], vf10, o1, 0, 0, 0);
                o1 = __builtin_amdgcn_mfma_f32_32x32x16_bf16(pu.v[1], vf11, o1, 0, 0, 0);
            }
            __builtin_amdgcn_s_setprio(0);
        }

        if (it + 1 < nit) {
            __syncthreads();                         // all waves done with LDS
            *(u16x8*)&KsT[ks][skr][skc]     = ka;
            *(u16x8*)&KsT[ks][skr][skc + 8] = kb;
            #pragma unroll
            for (int j = 0; j < 8; ++j) {
                VtT[ks][svc + j][svr]     = va[j];
                VtT[ks][svc + 8 + j][svr] = vb[j];
            }
        }
    }

    // ---- merge streams: O* = (a0 O0 + a1 O1) / (a0 l0 + a1 l1) ----
    __syncthreads();                                 // tile LDS dead; reuse
    if (ks == 0) {
        #pragma unroll
        for (int r = 0; r < 16; ++r) {
            int rl = (r & 3) + 8 * (r >> 2) + 4 * hi;
            Om[rg][rl][c]      = o0[r];
            Om[rg][rl][c + 32] = o1[r];
        }
        if (hi == 0) {
            ml[(rg << 5) + c][0] = m;
            ml[(rg << 5) + c][1] = lsum;
        }
    }
    __syncthreads();
    if (ks == 1) {
        float m0 = ml[(rg << 5) + c][0];
        float l0 = ml[(rg << 5) + c][1];
        float mstar = fmaxf(m0, m);
        float a0 = exp2f(m0 - mstar);
        float a1 = exp2f(m - mstar);
        float inv = 1.0f / (a0 * l0 + a1 * lsum);
        float f0 = a0 * inv, f1 = a1 * inv;
        #pragma unroll
        for (int r = 0; r < 16; ++r) {
            int rl = (r & 3) + 8 * (r >> 2) + 4 * hi;
            float f0r = __shfl(f0, rl, 32);
            float f1r = __shfl(f1, rl, 32);
            int grow = qb * 128 + rg * 32 + rl;
            size_t base = (size_t)grow * DMODEL + h * HDIM + c;
            ctx[base]      = f2bf(f0r * Om[rg][rl][c]      + f1r * o0[r]);
            ctx[base + 32] = f2bf(f0r * Om[rg][rl][c + 32] + f1r * o1[r]);
        }
    }
}

extern "C" void kernel_launch(void* const* d_in, const int* in_sizes, int n_in,
                              void* d_out, int out_size, void* d_ws, size_t ws_size,
                              hipStream_t stream) {
    const float* x  = (const float*)d_in[0];
    // d_in[1] = causal mask (tril by construction) — unused
    const float* Wq = (const float*)d_in[2];
    const float* Wk = (const float*)d_in[3];
    const float* Wv = (const float*)d_in[4];
    const float* Wo = (const float*)d_in[5];

    // ws layout (peak 35 MB):
    //   [0,0.5M) ctab  [0.5M,1M) stab
    //   [1M,9M)  ctx  (overlays Wtq/Wtk/Wtv, dead after QKV gemm)
    //   [1M,3M) Wtq  [3M,5M) Wtk  [5M,7M) Wtv
    //   [9M,11M) Wto
    //   [11M,19M) kr  [19M,27M) vb  [27M,35M) qr
    char* ws = (char*)d_ws;
    float* ctab = (float*)(ws);
    float* stab = (float*)(ws + (512u << 10));
    unsigned short* ctx = (unsigned short*)(ws + (1u  << 20));
    unsigned short* Wtq = (unsigned short*)(ws + (1u  << 20));
    unsigned short* Wtk = (unsigned short*)(ws + (3u  << 20));
    unsigned short* Wtv = (unsigned short*)(ws + (5u  << 20));
    unsigned short* Wto = (unsigned short*)(ws + (9u  << 20));
    unsigned short* kr  = (unsigned short*)(ws + (11u << 20));
    unsigned short* vb  = (unsigned short*)(ws + (19u << 20));
    unsigned short* qr  = (unsigned short*)(ws + (27u << 20));

    rope_table_kernel<<<(S_LEN * 32) / 256, 256, 0, stream>>>(ctab, stab);
    cvt_wt_kernel<<<dim3(16, 16, 4), 256, 0, stream>>>(Wq, Wk, Wv, Wo, Wtq, Wtk, Wtv, Wto);
    gemm_kernel<1><<<dim3(8, 32, 3), 256, 0, stream>>>(x, nullptr, Wtq, Wtk, Wtv,
                                                       qr, kr, vb, nullptr, ctab, stab);
    attn_kernel<<<dim3(16, 32), 512, 0, stream>>>(qr, kr, vb, ctx);
    gemm_kernel<0><<<dim3(8, 32, 1), 256, 0, stream>>>(nullptr, ctx, Wto, nullptr, nullptr,
                                                       nullptr, nullptr, nullptr,
                                                       (float*)d_out, ctab, stab);
}

// Round 11
// 184.291 us; speedup vs baseline: 1.4566x; 1.1473x over previous
//
#include <hip/hip_runtime.h>
#include <hip/hip_bf16.h>
#include <stdint.h>
#include <stddef.h>

#define S_LEN 4096
#define DMODEL 1024
#define NHEAD 16
#define HDIM 64
#define L2E 1.4426950408889634f

typedef __attribute__((ext_vector_type(8))) short bf16x8;
typedef __attribute__((ext_vector_type(8))) unsigned short u16x8;
typedef __attribute__((ext_vector_type(4))) float f32x4;
typedef __attribute__((ext_vector_type(16))) float f32x16;

__device__ __forceinline__ unsigned short f2bf(float f) {
    unsigned int u = __float_as_uint(f);
    return (unsigned short)((u + 0x7FFFu + ((u >> 16) & 1u)) >> 16);
}

// ---------------- RoPE table: cos/sin [4096][32] ----------------
__global__ __launch_bounds__(256) void rope_table_kernel(float* __restrict__ ctab,
                                                         float* __restrict__ stab) {
    int i = blockIdx.x * 256 + threadIdx.x;
    int s = i >> 5, j = i & 31;
    float freq = exp2f(-0.41524101186092407f * (float)j);   // 10000^(-j/32)
    float ang = (float)s * freq;
    ctab[i] = cosf(ang);
    stab[i] = sinf(ang);
}

// ---------------- x f32 -> bf16, once (removes per-K-step convert from GEMM) ----
__global__ __launch_bounds__(256) void cvt_x_kernel(const float* __restrict__ x,
                                                    unsigned short* __restrict__ xb) {
    int i = (blockIdx.x * 256 + threadIdx.x) * 8;
    f32x4 a = *(const f32x4*)(x + i);
    f32x4 b = *(const f32x4*)(x + i + 4);
    u16x8 o;
    #pragma unroll
    for (int j = 0; j < 4; ++j) { o[j] = f2bf(a[j]); o[4 + j] = f2bf(b[j]); }
    *(u16x8*)(xb + i) = o;
}

// ---------------- W [K][N] f32 -> Wt [N][K] bf16 (transpose) ----------------
__global__ __launch_bounds__(256) void cvt_wt_kernel(
    const float* __restrict__ w0, const float* __restrict__ w1,
    const float* __restrict__ w2, const float* __restrict__ w3,
    unsigned short* __restrict__ t0, unsigned short* __restrict__ t1,
    unsigned short* __restrict__ t2, unsigned short* __restrict__ t3) {
    const float* src; unsigned short* dst;
    switch (blockIdx.z) {
        case 0: src = w0; dst = t0; break;
        case 1: src = w1; dst = t1; break;
        case 2: src = w2; dst = t2; break;
        default: src = w3; dst = t3; break;
    }
    __shared__ float tile[64][65];
    int t = threadIdx.x;
    int k0 = blockIdx.y * 64, n0 = blockIdx.x * 64;
    int r = t >> 2, q4 = (t & 3) * 16;
    const float* sp = src + (size_t)(k0 + r) * DMODEL + n0 + q4;
    #pragma unroll
    for (int j = 0; j < 4; ++j) {
        f32x4 v = *(const f32x4*)(sp + j * 4);
        #pragma unroll
        for (int e = 0; e < 4; ++e) tile[r][q4 + j * 4 + e] = v[e];
    }
    __syncthreads();
    int n = t >> 2, kq = (t & 3) * 16;
    unsigned short* dp = dst + (size_t)(n0 + n) * DMODEL + k0 + kq;
    u16x8 a, b;
    #pragma unroll
    for (int j = 0; j < 8; ++j) { a[j] = f2bf(tile[kq + j][n]); b[j] = f2bf(tile[kq + 8 + j][n]); }
    *(u16x8*)dp = a;
    *(u16x8*)(dp + 8) = b;
}

// ---------------- GEMM 128x128x64, 4 waves, 16x16x32 bf16 MFMA ----------------
// A is always bf16 now. MODE 1: z selects q/k/v output, z<2 RoPE epilogue,
// z==0 scales by 0.125*L2E (log2-domain scores), bf16 stores.
// MODE 0: f32 store to fo (d_out).
template<int MODE>
__global__ __launch_bounds__(256) void gemm_kernel(
    const unsigned short* __restrict__ Ab,
    const unsigned short* __restrict__ B0,
    const unsigned short* __restrict__ B1,
    const unsigned short* __restrict__ B2,
    unsigned short* __restrict__ o0,
    unsigned short* __restrict__ o1,
    unsigned short* __restrict__ o2,
    float* __restrict__ fo,
    const float* __restrict__ ctab,
    const float* __restrict__ stab) {
    int z = blockIdx.z;
    const unsigned short* Bt = (MODE == 0) ? B0 : (z == 0 ? B0 : (z == 1 ? B1 : B2));
    unsigned short* outp     = (MODE == 0) ? o0 : (z == 0 ? o0 : (z == 1 ? o1 : o2));
    int m0 = blockIdx.y * 128, n0 = blockIdx.x * 128;
    __shared__ unsigned short As[128][72];
    __shared__ unsigned short Bs[128][72];
    int t = threadIdx.x, w = t >> 6, l = t & 63;
    int wm = w >> 1, wn = w & 1, g = l >> 4, c = l & 15;

    f32x4 acc[4][4];
    #pragma unroll
    for (int m = 0; m < 4; ++m)
        #pragma unroll
        for (int n = 0; n < 4; ++n) acc[m][n] = (f32x4){0.f, 0.f, 0.f, 0.f};

    int sr = t >> 1, scc = (t & 1) * 32;

    for (int kt = 0; kt < DMODEL; kt += 64) {
        __syncthreads();
        {
            const unsigned short* gp = Ab + (size_t)(m0 + sr) * DMODEL + kt + scc;
            #pragma unroll
            for (int j = 0; j < 4; ++j)
                *(u16x8*)&As[sr][scc + j * 8] = *(const u16x8*)(gp + j * 8);
        }
        {
            const unsigned short* gp = Bt + (size_t)(n0 + sr) * DMODEL + kt + scc;
            #pragma unroll
            for (int j = 0; j < 4; ++j)
                *(u16x8*)&Bs[sr][scc + j * 8] = *(const u16x8*)(gp + j * 8);
        }
        __syncthreads();
        #pragma unroll
        for (int kk = 0; kk < 64; kk += 32) {
            bf16x8 af[4], bf[4];
            #pragma unroll
            for (int m = 0; m < 4; ++m) af[m] = *(const bf16x8*)&As[wm * 64 + m * 16 + c][kk + g * 8];
            #pragma unroll
            for (int n = 0; n < 4; ++n) bf[n] = *(const bf16x8*)&Bs[wn * 64 + n * 16 + c][kk + g * 8];
            #pragma unroll
            for (int m = 0; m < 4; ++m)
                #pragma unroll
                for (int n = 0; n < 4; ++n)
                    acc[m][n] = __builtin_amdgcn_mfma_f32_16x16x32_bf16(af[m], bf[n], acc[m][n], 0, 0, 0);
        }
    }

    if (MODE == 1 && z < 2) {
        // q: fold 1/sqrt(64) AND log2(e) so attention scores are in log2 domain
        float sc8 = (z == 0) ? 0.125f * L2E : 1.0f;
        #pragma unroll
        for (int m = 0; m < 4; ++m) {
            #pragma unroll
            for (int r = 0; r < 4; ++r) {
                int srow = m0 + wm * 64 + m * 16 + g * 4 + r;
                #pragma unroll
                for (int n = 0; n < 2; ++n) {
                    int e = n * 16 + c;                      // e < 32 within head
                    float cs = ctab[srow * 32 + e];
                    float sn = stab[srow * 32 + e];
                    float lo = acc[m][n][r], hi = acc[m][n + 2][r];
                    float nlo = (lo * cs - hi * sn) * sc8;
                    float nhi = (hi * cs + lo * sn) * sc8;
                    size_t base = (size_t)srow * DMODEL + n0 + wn * 64;
                    outp[base + n * 16 + c]       = f2bf(nlo);
                    outp[base + (n + 2) * 16 + c] = f2bf(nhi);
                }
            }
        }
    } else if (MODE == 1) {
        #pragma unroll
        for (int m = 0; m < 4; ++m)
            #pragma unroll
            for (int r = 0; r < 4; ++r) {
                int srow = m0 + wm * 64 + m * 16 + g * 4 + r;
                size_t base = (size_t)srow * DMODEL + n0 + wn * 64;
                #pragma unroll
                for (int n = 0; n < 4; ++n)
                    outp[base + n * 16 + c] = f2bf(acc[m][n][r]);
            }
    } else {
        #pragma unroll
        for (int m = 0; m < 4; ++m)
            #pragma unroll
            for (int r = 0; r < 4; ++r) {
                int srow = m0 + wm * 64 + m * 16 + g * 4 + r;
                size_t base = (size_t)srow * DMODEL + n0 + wn * 64;
                #pragma unroll
                for (int n = 0; n < 4; ++n)
                    fo[base + n * 16 + c] = acc[m][n][r];
            }
    }
}

// ---------------- causal flash attention, 32x32 swapped-QK^T, in-reg softmax ----
// v5: as v4 (512 thr = 4 row-groups x 2 key-streams, exact f32 merge) plus
// zigzag qb mapping so co-resident block pairs have ~constant total work.
__global__ __launch_bounds__(512) void attn_kernel(
    const unsigned short* __restrict__ q,
    const unsigned short* __restrict__ k,
    const unsigned short* __restrict__ v,
    unsigned short* __restrict__ ctx) {
    int h = blockIdx.x;                              // head -> XCD cluster
    int yy = (int)blockIdx.y;
    int qb = (yy < 16) ? (31 - yy) : (yy - 16);      // zigzag: big+small pairing
    int t = threadIdx.x, w = t >> 6, l = t & 63, c = l & 31, hi = l >> 5;
    int rg = w & 3, ks = w >> 2;                     // row-group, key-stream

    __shared__ __align__(16) char smraw[36864];
    unsigned short (*KsT)[64][72] = (unsigned short (*)[64][72])smraw;           // [2][64][72]
    unsigned short (*VtT)[64][72] = (unsigned short (*)[64][72])(smraw + 18432); // [2][64][72]
    float (*Om)[32][64] = (float (*)[32][64])smraw;                              // [4][32][64]
    float (*ml)[2]      = (float (*)[2])(smraw + 32768);                         // [128][2]

    int qrow = qb * 128 + rg * 32 + c;               // this lane's q-row
    int wrmax = qb * 128 + rg * 32 + 31;

    bf16x8 qf[4];
    {
        const unsigned short* qp = q + (size_t)qrow * DMODEL + h * HDIM + hi * 8;
        #pragma unroll
        for (int s = 0; s < 4; ++s) qf[s] = *(const bf16x8*)(qp + s * 16);
    }

    f32x16 o0, o1;
    #pragma unroll
    for (int i = 0; i < 16; ++i) { o0[i] = 0.f; o1[i] = 0.f; }
    float m = -3.0e38f, lsum = 0.f;

    int ts = t & 255;
    int skr = ts >> 2, skc = (ts & 3) * 16;
    int svr = ts & 63, svc = ((ts >> 6) & 3) * 16;
    const unsigned short* gkb = k + (size_t)skr * DMODEL + h * HDIM + skc;
    const unsigned short* gvb = v + (size_t)svr * DMODEL + h * HDIM + svc;

    int nit = qb + 1;                                // tiles per stream
    u16x8 ka, kb, va, vb;
    {   // prologue: stream's tile 0 = global tile index ks
        size_t off = (size_t)(ks * 64) * DMODEL;
        ka = *(const u16x8*)(gkb + off);
        kb = *(const u16x8*)(gkb + off + 8);
        va = *(const u16x8*)(gvb + off);
        vb = *(const u16x8*)(gvb + off + 8);
    }
    *(u16x8*)&KsT[ks][skr][skc]     = ka;
    *(u16x8*)&KsT[ks][skr][skc + 8] = kb;
    #pragma unroll
    for (int j = 0; j < 8; ++j) {
        VtT[ks][svc + j][svr]     = va[j];
        VtT[ks][svc + 8 + j][svr] = vb[j];
    }

    for (int it = 0; it < nit; ++it) {
        int kt = 2 * it + ks;                        // my stream's tile
        int kv0 = kt * 64;
        if (it + 1 < nit) {                          // prefetch tile kt+2
            size_t off = (size_t)(kv0 + 128) * DMODEL;
            ka = *(const u16x8*)(gkb + off);
            kb = *(const u16x8*)(gkb + off + 8);
            va = *(const u16x8*)(gvb + off);
            vb = *(const u16x8*)(gvb + off + 8);
        }
        __syncthreads();                             // tiles staged

        #pragma unroll
        for (int h2 = 0; h2 < 2; ++h2) {
            int kbase = kv0 + h2 * 32;
            if (kbase > wrmax) continue;             // fully-masked half

            f32x16 sf;
            #pragma unroll
            for (int i = 0; i < 16; ++i) sf[i] = 0.f;
            __builtin_amdgcn_s_setprio(1);
            #pragma unroll
            for (int s = 0; s < 4; ++s) {
                bf16x8 kf = *(const bf16x8*)&KsT[ks][h2 * 32 + c][s * 16 + hi * 8];
                sf = __builtin_amdgcn_mfma_f32_32x32x16_bf16(kf, qf[s], sf, 0, 0, 0);
            }
            __builtin_amdgcn_s_setprio(0);

            if (kbase + 31 >= wrmax) {               // diagonal half: causal mask
                #pragma unroll
                for (int r = 0; r < 16; ++r) {
                    int key = kbase + (r & 3) + 8 * (r >> 2) + 4 * hi;
                    if (key > qrow) sf[r] = -3.0e38f;
                }
            }

            float tm = sf[0];
            #pragma unroll
            for (int r = 1; r < 16; ++r) tm = fmaxf(tm, sf[r]);
            tm = fmaxf(tm, __shfl_xor(tm, 32, 64));

            if (!__all(tm <= m + 8.f)) {             // rescale (rare: defer-max)
                float mn = fmaxf(m, tm);
                float al = exp2f(m - mn);
                m = mn;
                lsum *= al;
                #pragma unroll
                for (int r = 0; r < 16; ++r) {
                    float ar = __shfl(al, (r & 3) + 8 * (r >> 2) + 4 * hi, 32);
                    o0[r] *= ar;
                    o1[r] *= ar;
                }
            }

            float ps = 0.f;
            unsigned int dw[8];
            #pragma unroll
            for (int j = 0; j < 8; ++j) {
                float p0 = exp2f(sf[2 * j]     - m);
                float p1 = exp2f(sf[2 * j + 1] - m);
                unsigned int u0 = __float_as_uint(p0) & 0xFFFF0000u;
                unsigned int u1 = __float_as_uint(p1) & 0xFFFF0000u;
                ps += __uint_as_float(u0) + __uint_as_float(u1);
                dw[j] = (u0 >> 16) | u1;
            }
            ps += __shfl_xor(ps, 32, 64);
            lsum += ps;

            {   // repack to PV A-fragment
                auto r0 = __builtin_amdgcn_permlane32_swap(dw[0], dw[2], false, false);
                dw[0] = r0[0]; dw[2] = r0[1];
                auto r1 = __builtin_amdgcn_permlane32_swap(dw[1], dw[3], false, false);
                dw[1] = r1[0]; dw[3] = r1[1];
                auto r2 = __builtin_amdgcn_permlane32_swap(dw[4], dw[6], false, false);
                dw[4] = r2[0]; dw[6] = r2[1];
                auto r3 = __builtin_amdgcn_permlane32_swap(dw[5], dw[7], false, false);
                dw[5] = r3[0]; dw[7] = r3[1];
            }
            union { unsigned int u[8]; bf16x8 v[2]; } pu;
            #pragma unroll
            for (int j = 0; j < 8; ++j) pu.u[j] = dw[j];

            __builtin_amdgcn_s_setprio(1);
            {
                bf16x8 vf00 = *(const bf16x8*)&VtT[ks][c][h2 * 32 + hi * 8];
                bf16x8 vf01 = *(const bf16x8*)&VtT[ks][c][h2 * 32 + 16 + hi * 8];
                bf16x8 vf10 = *(const bf16x8*)&VtT[ks][32 + c][h2 * 32 + hi * 8];
                bf16x8 vf11 = *(const bf16x8*)&VtT[ks][32 + c][h2 * 32 + 16 + hi * 8];
                o0 = __builtin_amdgcn_mfma_f32_32x32x16_bf16(pu.v[0], vf00, o0, 0, 0, 0);
                o0 = __builtin_amdgcn_mfma_f32_32x32x16_bf16(pu.v[1], vf01, o0, 0, 0, 0);
                o1 = __builtin_amdgcn_mfma_f32_32x32x16_bf16(pu.v[0], vf10, o1, 0, 0, 0);
                o1 = __builtin_amdgcn_mfma_f32_32x32x16_bf16(pu.v[1], vf11, o1, 0, 0, 0);
            }
            __builtin_amdgcn_s_setprio(0);
        }

        if (it + 1 < nit) {
            __syncthreads();                         // all waves done with LDS
            *(u16x8*)&KsT[ks][skr][skc]     = ka;
            *(u16x8*)&KsT[ks][skr][skc + 8] = kb;
            #pragma unroll
            for (int j = 0; j < 8; ++j) {
                VtT[ks][svc + j][svr]     = va[j];
                VtT[ks][svc + 8 + j][svr] = vb[j];
            }
        }
    }

    // ---- merge streams: O* = (a0 O0 + a1 O1) / (a0 l0 + a1 l1) ----
    __syncthreads();                                 // tile LDS dead; reuse
    if (ks == 0) {
        #pragma unroll
        for (int r = 0; r < 16; ++r) {
            int rl = (r & 3) + 8 * (r >> 2) + 4 * hi;
            Om[rg][rl][c]      = o0[r];
            Om[rg][rl][c + 32] = o1[r];
        }
        if (hi == 0) {
            ml[(rg << 5) + c][0] = m;
            ml[(rg << 5) + c][1] = lsum;
        }
    }
    __syncthreads();
    if (ks == 1) {
        float m0 = ml[(rg << 5) + c][0];
        float l0 = ml[(rg << 5) + c][1];
        float mstar = fmaxf(m0, m);
        float a0 = exp2f(m0 - mstar);
        float a1 = exp2f(m - mstar);
        float inv = 1.0f / (a0 * l0 + a1 * lsum);
        float f0 = a0 * inv, f1 = a1 * inv;
        #pragma unroll
        for (int r = 0; r < 16; ++r) {
            int rl = (r & 3) + 8 * (r >> 2) + 4 * hi;
            float f0r = __shfl(f0, rl, 32);
            float f1r = __shfl(f1, rl, 32);
            int grow = qb * 128 + rg * 32 + rl;
            size_t base = (size_t)grow * DMODEL + h * HDIM + c;
            ctx[base]      = f2bf(f0r * Om[rg][rl][c]      + f1r * o0[r]);
            ctx[base + 32] = f2bf(f0r * Om[rg][rl][c + 32] + f1r * o1[r]);
        }
    }
}

extern "C" void kernel_launch(void* const* d_in, const int* in_sizes, int n_in,
                              void* d_out, int out_size, void* d_ws, size_t ws_size,
                              hipStream_t stream) {
    const float* x  = (const float*)d_in[0];
    // d_in[1] = causal mask (tril by construction) — unused
    const float* Wq = (const float*)d_in[2];
    const float* Wk = (const float*)d_in[3];
    const float* Wv = (const float*)d_in[4];
    const float* Wo = (const float*)d_in[5];

    // ws layout (peak 43 MB):
    //   [0,0.5M) ctab  [0.5M,1M) stab
    //   [1M,9M)  ctx  (overlays Wtq/Wtk/Wtv, dead after QKV gemm)
    //   [1M,3M) Wtq  [3M,5M) Wtk  [5M,7M) Wtv
    //   [9M,11M) Wto
    //   [11M,19M) kr  [19M,27M) vb  [27M,35M) qr  [35M,43M) xb
    char* ws = (char*)d_ws;
    float* ctab = (float*)(ws);
    float* stab = (float*)(ws + (512u << 10));
    unsigned short* ctx = (unsigned short*)(ws + (1u  << 20));
    unsigned short* Wtq = (unsigned short*)(ws + (1u  << 20));
    unsigned short* Wtk = (unsigned short*)(ws + (3u  << 20));
    unsigned short* Wtv = (unsigned short*)(ws + (5u  << 20));
    unsigned short* Wto = (unsigned short*)(ws + (9u  << 20));
    unsigned short* kr  = (unsigned short*)(ws + (11u << 20));
    unsigned short* vb  = (unsigned short*)(ws + (19u << 20));
    unsigned short* qr  = (unsigned short*)(ws + (27u << 20));
    unsigned short* xb  = (unsigned short*)(ws + (35u << 20));

    rope_table_kernel<<<(S_LEN * 32) / 256, 256, 0, stream>>>(ctab, stab);
    cvt_x_kernel<<<(S_LEN * DMODEL) / 2048, 256, 0, stream>>>(x, xb);
    cvt_wt_kernel<<<dim3(16, 16, 4), 256, 0, stream>>>(Wq, Wk, Wv, Wo, Wtq, Wtk, Wtv, Wto);
    gemm_kernel<1><<<dim3(8, 32, 3), 256, 0, stream>>>(xb, Wtq, Wtk, Wtv,
                                                       qr, kr, vb, nullptr, ctab, stab);
    attn_kernel<<<dim3(16, 32), 512, 0, stream>>>(qr, kr, vb, ctx);
    gemm_kernel<0><<<dim3(8, 32, 1), 256, 0, stream>>>(ctx, Wto, nullptr, nullptr,
                                                       nullptr, nullptr, nullptr,
                                                       (float*)d_out, ctab, stab);
}